// Round 11
// baseline (196.731 us; speedup 1.0000x reference)
//
#include <hip/hip_runtime.h>
#include <hip/hip_bf16.h>

typedef __attribute__((ext_vector_type(4))) int   i32x4;
typedef __attribute__((ext_vector_type(8))) int   i32x8;
typedef __attribute__((ext_vector_type(16))) float f32x16;

#define C_DIM 512
#define SCALE 1.6487212707001282f            // exp(0.5)
#define S2LOG (SCALE * 1.4426950408889634f)  // exp(0.5) * log2(e)
#define NT 8                                  // C_DIM / 64 K-tiles

// -------- Kernel A: L2-normalize rows -> fp8 e4m3; exact fp32 diag; zero sumexp
__global__ __launch_bounds__(128) void cossim_normalize(
    const float* __restrict__ pred, const float* __restrict__ target,
    unsigned char* __restrict__ p8, unsigned char* __restrict__ t8,
    float* __restrict__ diag, float* __restrict__ sumexp) {
  const int n = blockIdx.x;
  const int t = threadIdx.x;  // 128 threads, 4 floats each = 512
  const float4* p4 = (const float4*)(pred + (size_t)n * C_DIM);
  const float4* q4 = (const float4*)(target + (size_t)n * C_DIM);
  float4 a = p4[t];
  float4 b = q4[t];
  float ssp = a.x*a.x + a.y*a.y + a.z*a.z + a.w*a.w;
  float sst = b.x*b.x + b.y*b.y + b.z*b.z + b.w*b.w;
  float dt  = a.x*b.x + a.y*b.y + a.z*b.z + a.w*b.w;
  #pragma unroll
  for (int off = 32; off > 0; off >>= 1) {
    ssp += __shfl_down(ssp, off);
    sst += __shfl_down(sst, off);
    dt  += __shfl_down(dt,  off);
  }
  __shared__ float red[3][2];
  const int wid = t >> 6;
  if ((t & 63) == 0) { red[0][wid] = ssp; red[1][wid] = sst; red[2][wid] = dt; }
  __syncthreads();
  const float tp = red[0][0] + red[0][1];
  const float tt = red[1][0] + red[1][1];
  const float td = red[2][0] + red[2][1];
  const float rnp = 1.0f / fmaxf(sqrtf(tp), 1e-12f);
  const float rnt = 1.0f / fmaxf(sqrtf(tt), 1e-12f);

  unsigned pw = (unsigned)__builtin_amdgcn_cvt_pk_fp8_f32(a.x * rnp, a.y * rnp, 0, false);
  pw = (unsigned)__builtin_amdgcn_cvt_pk_fp8_f32(a.z * rnp, a.w * rnp, (int)pw, true);
  unsigned tw = (unsigned)__builtin_amdgcn_cvt_pk_fp8_f32(b.x * rnt, b.y * rnt, 0, false);
  tw = (unsigned)__builtin_amdgcn_cvt_pk_fp8_f32(b.z * rnt, b.w * rnt, (int)tw, true);
  ((unsigned*)(p8 + (size_t)n * C_DIM))[t] = pw;
  ((unsigned*)(t8 + (size_t)n * C_DIM))[t] = tw;

  if (t == 0) {
    diag[n] = td * rnp * rnt * SCALE;  // exact fp32 diagonal, already scaled
    sumexp[n] = 0.0f;
  }
}

// -------- Kernel B: 128x128-tile fp8 MX-MFMA NT-GEMM (scales=1.0), 256 threads,
//          single-buffered in-place staging, fused sum-of-exp reduction.
//          NOTE: no min-waves clamp — forcing (256,3) starved the VGPR partition
//          (VGPR_Count=84) and spilled acc/frags: 330 MB scratch. Let RA breathe.
__device__ __forceinline__ void load_lds16(const void* gsrc, void* ldst) {
  __builtin_amdgcn_global_load_lds(
      (const __attribute__((address_space(1))) void*)gsrc,
      (__attribute__((address_space(3))) void*)ldst, 16, 0, 0);
}

__global__ __launch_bounds__(256) void cossim_gemm_lse(
    const unsigned char* __restrict__ P, const unsigned char* __restrict__ T,
    float* __restrict__ sumexp) {
  // fp8 tiles: A 128x64 = 8KB, B 128x64 = 8KB, rowsum 1KB -> 17KB LDS
  __shared__ unsigned char ldsA[128][64];
  __shared__ unsigned char ldsB[128][64];
  __shared__ float lds_rs[2][128];

  const int tid  = threadIdx.x;
  const int lane = tid & 63;
  const int w    = tid >> 6;   // 0..3
  const int wr   = w >> 1;     // wave row 0..1 (owns 64 C-rows)
  const int wc   = w & 1;      // wave col 0..1 (owns 64 C-cols)

  // L2-locality supertile swizzle, bijective on 4096 blocks = 64by x 64bx tiles.
  // Per XCD: 32by x 16bx region; 8 rounds of 8x8 supertiles (concurrent ~1.5MB < 4MB L2).
  const int xcd  = blockIdx.x & 7;
  const int slot = blockIdx.x >> 3;       // 0..511
  const int q    = slot >> 6;             // 0..7: round (4 x 2 supertile grid)
  const int v    = slot & 63;             // 0..63: position in 8x8 supertile
  const int by   = (xcd >> 2) * 32 + (q >> 1) * 8 + (v >> 3);  // 0..63
  const int bx   = (xcd & 3) * 16 + (q & 1) * 8 + (v & 7);     // 0..63
  const int brow = by * 128;
  const int bcol = bx * 128;

  const unsigned char* gA = P + (size_t)brow * C_DIM;
  const unsigned char* gB = T + (size_t)bcol * C_DIM;

  // Stage K-tile t (64 fp8 = 64B/row; 4 lanes x 16B per row, 16 rows per load_lds16).
  // LDS dest LINEAR; bank swizzle chunk ^= (row>>1)&3 via pre-swizzled GLOBAL source,
  // chosen so slot = 4*(r&1) + (c ^ ((r>>1)&3)) is bijective over r mod 8.
  auto stageA = [&](int t) {
    #pragma unroll
    for (int c = 0; c < 2; ++c) {
      const int rb  = w * 32 + c * 16;
      const int rr  = rb + (lane >> 2);
      const int gch = (lane & 3) ^ ((rr >> 1) & 3);
      load_lds16(gA + (size_t)rr * C_DIM + t * 64 + gch * 16, &ldsA[rb][0]);
    }
  };
  auto stageB = [&](int t) {
    #pragma unroll
    for (int c = 0; c < 2; ++c) {
      const int rb  = w * 32 + c * 16;
      const int rr  = rb + (lane >> 2);
      const int gch = (lane & 3) ^ ((rr >> 1) & 3);
      load_lds16(gB + (size_t)rr * C_DIM + t * 64 + gch * 16, &ldsB[rb][0]);
    }
  };

  // Fragment layout (32x32x64 f8): lane holds row=lane&31, k=(lane>>5)*32 + 0..31.
  const int arow0 = wr * 64 + (lane & 31);
  const int brow0 = wc * 64 + (lane & 31);
  const int c0    = (lane >> 5) * 2;  // logical 16B chunk base

  auto LDA = [&](int mm) -> i32x8 {
    const int r = arow0 + mm * 32;
    const int p = (r >> 1) & 3;
    const i32x4 lo = *(const i32x4*)&ldsA[r][((c0 + 0) ^ p) * 16];
    const i32x4 hi = *(const i32x4*)&ldsA[r][((c0 + 1) ^ p) * 16];
    return __builtin_shufflevector(lo, hi, 0, 1, 2, 3, 4, 5, 6, 7);
  };
  auto LDB = [&](int nn) -> i32x8 {
    const int r = brow0 + nn * 32;
    const int p = (r >> 1) & 3;
    const i32x4 lo = *(const i32x4*)&ldsB[r][((c0 + 0) ^ p) * 16];
    const i32x4 hi = *(const i32x4*)&ldsB[r][((c0 + 1) ^ p) * 16];
    return __builtin_shufflevector(lo, hi, 0, 1, 2, 3, 4, 5, 6, 7);
  };

  f32x16 acc[2][2] = {};

  // ---- prologue: stage tile 0; __syncthreads drains vmcnt
  stageA(0);
  stageB(0);
  __syncthreads();

  // ---- main loop: 2 barriers per K-tile, in-place restage by liveness
  for (int s = 0; s < NT; ++s) {
    i32x8 af0 = LDA(0), af1 = LDA(1);
    i32x8 bf0 = LDB(0), bf1 = LDB(1);

    __builtin_amdgcn_s_setprio(1);
    acc[0][0] = __builtin_amdgcn_mfma_scale_f32_32x32x64_f8f6f4(
        af0, bf0, acc[0][0], 0, 0, 0, 127, 0, 127);
    acc[0][1] = __builtin_amdgcn_mfma_scale_f32_32x32x64_f8f6f4(
        af0, bf1, acc[0][1], 0, 0, 0, 127, 0, 127);
    __builtin_amdgcn_s_setprio(0);

    __syncthreads();  // all waves' reads of tile s retired -> in-place restage safe

    if (s + 1 < NT) { stageA(s + 1); stageB(s + 1); }

    __builtin_amdgcn_s_setprio(1);
    acc[1][0] = __builtin_amdgcn_mfma_scale_f32_32x32x64_f8f6f4(
        af1, bf0, acc[1][0], 0, 0, 0, 127, 0, 127);
    acc[1][1] = __builtin_amdgcn_mfma_scale_f32_32x32x64_f8f6f4(
        af1, bf1, acc[1][1], 0, 0, 0, 127, 0, 127);
    __builtin_amdgcn_s_setprio(0);

    __syncthreads();  // drains vmcnt(0): staged tile visible
  }

  // ---- epilogue: exp + row-sum. C/D 32x32: col=lane&31, row=(r&3)+8*(r>>2)+4*(lane>>5)
  #pragma unroll
  for (int m = 0; m < 2; ++m) {
    #pragma unroll
    for (int r = 0; r < 16; ++r) {
      float x = exp2f(acc[m][0][r] * S2LOG) + exp2f(acc[m][1][r] * S2LOG);
      x += __shfl_xor(x, 1);
      x += __shfl_xor(x, 2);
      x += __shfl_xor(x, 4);
      x += __shfl_xor(x, 8);
      x += __shfl_xor(x, 16);
      if ((lane & 31) == 0)
        lds_rs[wc][wr * 64 + m * 32 + (r & 3) + 8 * (r >> 2) + (lane >> 5) * 4] = x;
    }
  }
  __syncthreads();
  if (tid < 128) {
    atomicAdd(&sumexp[brow + tid], lds_rs[0][tid] + lds_rs[1][tid]);
  }
}

// -------- Kernel C: loss = mean(log(sumexp) - diag), 1024 threads, float4 loads
__global__ __launch_bounds__(1024) void cossim_loss(
    const float* __restrict__ sumexp, const float* __restrict__ diag,
    float* __restrict__ out, int N) {
  const int tid = threadIdx.x;
  const float4* s4 = (const float4*)sumexp;
  const float4* d4 = (const float4*)diag;
  float s = 0.0f;
  for (int i = tid; i < N / 4; i += 1024) {
    float4 a = s4[i];
    float4 b = d4[i];
    s += (logf(a.x) - b.x) + (logf(a.y) - b.y) + (logf(a.z) - b.z) + (logf(a.w) - b.w);
  }
  #pragma unroll
  for (int off = 32; off > 0; off >>= 1) s += __shfl_down(s, off);
  __shared__ float red[16];
  if ((tid & 63) == 0) red[tid >> 6] = s;
  __syncthreads();
  if (tid == 0) {
    float t = 0.0f;
    #pragma unroll
    for (int i = 0; i < 16; ++i) t += red[i];
    out[0] = t / (float)N;
  }
}

extern "C" void kernel_launch(void* const* d_in, const int* in_sizes, int n_in,
                              void* d_out, int out_size, void* d_ws, size_t ws_size,
                              hipStream_t stream) {
  const int C = C_DIM;
  const int N = in_sizes[0] / C;  // 8192
  const float* pred   = (const float*)d_in[0];
  const float* target = (const float*)d_in[1];
  float* out = (float*)d_out;

  char* ws = (char*)d_ws;
  unsigned char* p8 = (unsigned char*)ws;
  unsigned char* t8 = (unsigned char*)(ws + (size_t)N * C);
  float* diag   = (float*)(ws + (size_t)2 * N * C);
  float* sumexp = diag + N;

  cossim_normalize<<<N, 128, 0, stream>>>(pred, target, p8, t8, diag, sumexp);
  const int nblk = (N / 128) * (N / 128);  // 4096
  cossim_gemm_lse<<<nblk, 256, 0, stream>>>(p8, t8, sumexp);
  cossim_loss<<<1, 1024, 0, stream>>>(sumexp, diag, out, N);
}

// Round 12
// 95.899 us; speedup vs baseline: 2.0514x; 2.0514x over previous
//
#include <hip/hip_runtime.h>
#include <hip/hip_bf16.h>

typedef __attribute__((ext_vector_type(4))) int   i32x4;
typedef __attribute__((ext_vector_type(8))) int   i32x8;
typedef __attribute__((ext_vector_type(16))) float f32x16;

#define C_DIM 512
#define SCALE 1.6487212707001282f            // exp(0.5)
#define S2LOG (SCALE * 1.4426950408889634f)  // exp(0.5) * log2(e)
#define NT 8                                  // C_DIM / 64 K-tiles

// -------- Kernel A: L2-normalize rows -> fp8 e4m3; exact fp32 diag; zero sumexp
__global__ __launch_bounds__(128) void cossim_normalize(
    const float* __restrict__ pred, const float* __restrict__ target,
    unsigned char* __restrict__ p8, unsigned char* __restrict__ t8,
    float* __restrict__ diag, float* __restrict__ sumexp) {
  const int n = blockIdx.x;
  const int t = threadIdx.x;  // 128 threads, 4 floats each = 512
  const float4* p4 = (const float4*)(pred + (size_t)n * C_DIM);
  const float4* q4 = (const float4*)(target + (size_t)n * C_DIM);
  float4 a = p4[t];
  float4 b = q4[t];
  float ssp = a.x*a.x + a.y*a.y + a.z*a.z + a.w*a.w;
  float sst = b.x*b.x + b.y*b.y + b.z*b.z + b.w*b.w;
  float dt  = a.x*b.x + a.y*b.y + a.z*b.z + a.w*b.w;
  #pragma unroll
  for (int off = 32; off > 0; off >>= 1) {
    ssp += __shfl_down(ssp, off);
    sst += __shfl_down(sst, off);
    dt  += __shfl_down(dt,  off);
  }
  __shared__ float red[3][2];
  const int wid = t >> 6;
  if ((t & 63) == 0) { red[0][wid] = ssp; red[1][wid] = sst; red[2][wid] = dt; }
  __syncthreads();
  const float tp = red[0][0] + red[0][1];
  const float tt = red[1][0] + red[1][1];
  const float td = red[2][0] + red[2][1];
  const float rnp = 1.0f / fmaxf(sqrtf(tp), 1e-12f);
  const float rnt = 1.0f / fmaxf(sqrtf(tt), 1e-12f);

  unsigned pw = (unsigned)__builtin_amdgcn_cvt_pk_fp8_f32(a.x * rnp, a.y * rnp, 0, false);
  pw = (unsigned)__builtin_amdgcn_cvt_pk_fp8_f32(a.z * rnp, a.w * rnp, (int)pw, true);
  unsigned tw = (unsigned)__builtin_amdgcn_cvt_pk_fp8_f32(b.x * rnt, b.y * rnt, 0, false);
  tw = (unsigned)__builtin_amdgcn_cvt_pk_fp8_f32(b.z * rnt, b.w * rnt, (int)tw, true);
  ((unsigned*)(p8 + (size_t)n * C_DIM))[t] = pw;
  ((unsigned*)(t8 + (size_t)n * C_DIM))[t] = tw;

  if (t == 0) {
    diag[n] = td * rnp * rnt * SCALE;  // exact fp32 diagonal, already scaled
    sumexp[n] = 0.0f;
  }
}

// -------- Kernel B: 128x128-tile fp8 MX-MFMA NT-GEMM (scales=1.0), 256 threads,
//          DOUBLE-buffered LDS, one barrier per K-tile, 2 blocks/CU guaranteed by
//          __launch_bounds__(256,2) (unified budget 256 >= ~200 demand: no spill).
__device__ __forceinline__ void load_lds16(const void* gsrc, void* ldst) {
  __builtin_amdgcn_global_load_lds(
      (const __attribute__((address_space(1))) void*)gsrc,
      (__attribute__((address_space(3))) void*)ldst, 16, 0, 0);
}

__global__ __launch_bounds__(256, 2) void cossim_gemm_lse(
    const unsigned char* __restrict__ P, const unsigned char* __restrict__ T,
    float* __restrict__ sumexp) {
  // fp8 tiles, double-buffered: 2 x (A 8KB + B 8KB) + rowsum 1KB = 33KB LDS
  __shared__ unsigned char ldsA[2][128][64];
  __shared__ unsigned char ldsB[2][128][64];
  __shared__ float lds_rs[2][128];

  const int tid  = threadIdx.x;
  const int lane = tid & 63;
  const int w    = tid >> 6;   // 0..3
  const int wr   = w >> 1;     // wave row 0..1 (owns 64 C-rows)
  const int wc   = w & 1;      // wave col 0..1 (owns 64 C-cols)

  // L2-locality supertile swizzle, bijective on 4096 blocks = 64by x 64bx tiles.
  // Per XCD: 32by x 16bx region; 8 rounds of 8x8 supertiles (concurrent ~1.5MB < 4MB L2).
  const int xcd  = blockIdx.x & 7;
  const int slot = blockIdx.x >> 3;       // 0..511
  const int q    = slot >> 6;             // 0..7: round (4 x 2 supertile grid)
  const int v    = slot & 63;             // 0..63: position in 8x8 supertile
  const int by   = (xcd >> 2) * 32 + (q >> 1) * 8 + (v >> 3);  // 0..63
  const int bx   = (xcd & 3) * 16 + (q & 1) * 8 + (v & 7);     // 0..63
  const int brow = by * 128;
  const int bcol = bx * 128;

  const unsigned char* gA = P + (size_t)brow * C_DIM;
  const unsigned char* gB = T + (size_t)bcol * C_DIM;

  // Stage K-tile t into buffer bi (64 fp8 = 64B/row; 4 lanes x 16B per row).
  // LDS dest LINEAR; bank swizzle chunk ^= (row>>1)&3 via pre-swizzled GLOBAL source,
  // chosen so slot = 4*(r&1) + (c ^ ((r>>1)&3)) is bijective over r mod 8.
  auto stageA = [&](int t, int bi) {
    #pragma unroll
    for (int c = 0; c < 2; ++c) {
      const int rb  = w * 32 + c * 16;
      const int rr  = rb + (lane >> 2);
      const int gch = (lane & 3) ^ ((rr >> 1) & 3);
      load_lds16(gA + (size_t)rr * C_DIM + t * 64 + gch * 16, &ldsA[bi][rb][0]);
    }
  };
  auto stageB = [&](int t, int bi) {
    #pragma unroll
    for (int c = 0; c < 2; ++c) {
      const int rb  = w * 32 + c * 16;
      const int rr  = rb + (lane >> 2);
      const int gch = (lane & 3) ^ ((rr >> 1) & 3);
      load_lds16(gB + (size_t)rr * C_DIM + t * 64 + gch * 16, &ldsB[bi][rb][0]);
    }
  };

  // Fragment layout (32x32x64 f8): lane holds row=lane&31, k=(lane>>5)*32 + 0..31.
  const int arow0 = wr * 64 + (lane & 31);
  const int brow0 = wc * 64 + (lane & 31);
  const int c0    = (lane >> 5) * 2;  // logical 16B chunk base

  auto LDA = [&](int bi, int mm) -> i32x8 {
    const int r = arow0 + mm * 32;
    const int p = (r >> 1) & 3;
    const i32x4 lo = *(const i32x4*)&ldsA[bi][r][((c0 + 0) ^ p) * 16];
    const i32x4 hi = *(const i32x4*)&ldsA[bi][r][((c0 + 1) ^ p) * 16];
    return __builtin_shufflevector(lo, hi, 0, 1, 2, 3, 4, 5, 6, 7);
  };
  auto LDB = [&](int bi, int nn) -> i32x8 {
    const int r = brow0 + nn * 32;
    const int p = (r >> 1) & 3;
    const i32x4 lo = *(const i32x4*)&ldsB[bi][r][((c0 + 0) ^ p) * 16];
    const i32x4 hi = *(const i32x4*)&ldsB[bi][r][((c0 + 1) ^ p) * 16];
    return __builtin_shufflevector(lo, hi, 0, 1, 2, 3, 4, 5, 6, 7);
  };

  f32x16 acc[2][2] = {};

  // ---- prologue: stage tile 0 into buf 0; barrier drains vmcnt
  stageA(0, 0);
  stageB(0, 0);
  __syncthreads();

  // ---- main loop: 1 barrier per K-tile; stage s+1 overlaps compute of s
  #pragma unroll 2
  for (int s = 0; s < NT; ++s) {
    const int buf  = s & 1;
    const int nbuf = buf ^ 1;

    if (s + 1 < NT) { stageA(s + 1, nbuf); stageB(s + 1, nbuf); }  // 4 gload_lds

    i32x8 af0 = LDA(buf, 0), af1 = LDA(buf, 1);
    i32x8 bf0 = LDB(buf, 0), bf1 = LDB(buf, 1);

    __builtin_amdgcn_s_setprio(1);
    acc[0][0] = __builtin_amdgcn_mfma_scale_f32_32x32x64_f8f6f4(
        af0, bf0, acc[0][0], 0, 0, 0, 127, 0, 127);
    acc[0][1] = __builtin_amdgcn_mfma_scale_f32_32x32x64_f8f6f4(
        af0, bf1, acc[0][1], 0, 0, 0, 127, 0, 127);
    acc[1][0] = __builtin_amdgcn_mfma_scale_f32_32x32x64_f8f6f4(
        af1, bf0, acc[1][0], 0, 0, 0, 127, 0, 127);
    acc[1][1] = __builtin_amdgcn_mfma_scale_f32_32x32x64_f8f6f4(
        af1, bf1, acc[1][1], 0, 0, 0, 127, 0, 127);
    __builtin_amdgcn_s_setprio(0);

    __syncthreads();  // drains vmcnt(0): next tile staged & this tile's reads done
  }

  // ---- epilogue: exp + row-sum. C/D 32x32: col=lane&31, row=(r&3)+8*(r>>2)+4*(lane>>5)
  #pragma unroll
  for (int m = 0; m < 2; ++m) {
    #pragma unroll
    for (int r = 0; r < 16; ++r) {
      float x = exp2f(acc[m][0][r] * S2LOG) + exp2f(acc[m][1][r] * S2LOG);
      x += __shfl_xor(x, 1);
      x += __shfl_xor(x, 2);
      x += __shfl_xor(x, 4);
      x += __shfl_xor(x, 8);
      x += __shfl_xor(x, 16);
      if ((lane & 31) == 0)
        lds_rs[wc][wr * 64 + m * 32 + (r & 3) + 8 * (r >> 2) + (lane >> 5) * 4] = x;
    }
  }
  __syncthreads();
  if (tid < 128) {
    atomicAdd(&sumexp[brow + tid], lds_rs[0][tid] + lds_rs[1][tid]);
  }
}

// -------- Kernel C: loss = mean(log(sumexp) - diag), 1024 threads, float4 loads
__global__ __launch_bounds__(1024) void cossim_loss(
    const float* __restrict__ sumexp, const float* __restrict__ diag,
    float* __restrict__ out, int N) {
  const int tid = threadIdx.x;
  const float4* s4 = (const float4*)sumexp;
  const float4* d4 = (const float4*)diag;
  float s = 0.0f;
  for (int i = tid; i < N / 4; i += 1024) {
    float4 a = s4[i];
    float4 b = d4[i];
    s += (logf(a.x) - b.x) + (logf(a.y) - b.y) + (logf(a.z) - b.z) + (logf(a.w) - b.w);
  }
  #pragma unroll
  for (int off = 32; off > 0; off >>= 1) s += __shfl_down(s, off);
  __shared__ float red[16];
  if ((tid & 63) == 0) red[tid >> 6] = s;
  __syncthreads();
  if (tid == 0) {
    float t = 0.0f;
    #pragma unroll
    for (int i = 0; i < 16; ++i) t += red[i];
    out[0] = t / (float)N;
  }
}

extern "C" void kernel_launch(void* const* d_in, const int* in_sizes, int n_in,
                              void* d_out, int out_size, void* d_ws, size_t ws_size,
                              hipStream_t stream) {
  const int C = C_DIM;
  const int N = in_sizes[0] / C;  // 8192
  const float* pred   = (const float*)d_in[0];
  const float* target = (const float*)d_in[1];
  float* out = (float*)d_out;

  char* ws = (char*)d_ws;
  unsigned char* p8 = (unsigned char*)ws;
  unsigned char* t8 = (unsigned char*)(ws + (size_t)N * C);
  float* diag   = (float*)(ws + (size_t)2 * N * C);
  float* sumexp = diag + N;

  cossim_normalize<<<N, 128, 0, stream>>>(pred, target, p8, t8, diag, sumexp);
  const int nblk = (N / 128) * (N / 128);  // 4096
  cossim_gemm_lse<<<nblk, 256, 0, stream>>>(p8, t8, sumexp);
  cossim_loss<<<1, 1024, 0, stream>>>(sumexp, diag, out, N);
}